// Round 15
// baseline (106.676 us; speedup 1.0000x reference)
//
#include <hip/hip_runtime.h>
#include <stdint.h>

// DigitCaps with O=1: routing softmax over one out-capsule is identity, so
// the reference reduces to
//   s[b,v]  = sum_{i,d} W[i,v,d] * x[b,i,d]        (M=32, N=512, K=32768 GEMM)
//   out     = s * sqrt(sq)/(1+sq),  sq = sum_v s^2  (per-b squash)
// Both tuple outputs (t, outputs) are identical [32,1,512] tensors.
//
// R15: final consolidation. R14 confirmed caps_mfma is at/near its HBM
// stream floor; remaining fat = LDS epilogue traffic + reduce size. KSW
// 32->64 (4 straight-line ksteps/wave, 16 VMEM in flight) -> KB=32, 512
// blocks = exactly 2 blocks/CU; grid LDS epilogue halves again (64->32 MB),
// partial 1 MB. Fixed harness floor: ~82.5us of 0xAA workspace fills.

#define NB 32
#define NI 4096
#define NV 512
#define ND 8
#define NK 32768            // K = NI*ND
#define KB 32               // k-blocks (partial slices)
#define KSB (NK / KB)       // 1024 k per block (16 waves x 64)
#define KSW 64              // 64 k per wave = four 32x32x16 MFMA steps
#define NST 4               // ksteps per wave

typedef __fp16 f16x8 __attribute__((ext_vector_type(8)));
typedef __fp16 f16x2 __attribute__((ext_vector_type(2)));
typedef float  f32x16 __attribute__((ext_vector_type(16)));

// ---------------------------------------------------------------------------
// Kernel 1: split x (fp32 [32][32768]) into f16 hi/lo planes in FRAGMENT
// order: xt[(g*32 + b)*8 + j] where g=k>>3, j=k&7. hi = rtz(x); lo = x - hi.
// ---------------------------------------------------------------------------
__global__ __launch_bounds__(256) void x_prep(
    const float* __restrict__ x, __fp16* __restrict__ xh,
    __fp16* __restrict__ xl)
{
    const int tid = blockIdx.x * 256 + threadIdx.x;   // 131072 total
    const int b = tid & 31;
    const int g = tid >> 5;

    const float4* xp = (const float4*)(x + (size_t)b * NK + (size_t)g * 8);
    const float4 f0 = xp[0];
    const float4 f1 = xp[1];

    const f16x2 h0 = __builtin_amdgcn_cvt_pkrtz(f0.x, f0.y);
    const f16x2 h1 = __builtin_amdgcn_cvt_pkrtz(f0.z, f0.w);
    const f16x2 h2 = __builtin_amdgcn_cvt_pkrtz(f1.x, f1.y);
    const f16x2 h3 = __builtin_amdgcn_cvt_pkrtz(f1.z, f1.w);
    const f16x2 l0 = __builtin_amdgcn_cvt_pkrtz(f0.x - (float)h0.x, f0.y - (float)h0.y);
    const f16x2 l1 = __builtin_amdgcn_cvt_pkrtz(f0.z - (float)h1.x, f0.w - (float)h1.y);
    const f16x2 l2 = __builtin_amdgcn_cvt_pkrtz(f1.x - (float)h2.x, f1.y - (float)h2.y);
    const f16x2 l3 = __builtin_amdgcn_cvt_pkrtz(f1.z - (float)h3.x, f1.w - (float)h3.y);

    const f16x8 h = {h0.x, h0.y, h1.x, h1.y, h2.x, h2.y, h3.x, h3.y};
    const f16x8 l = {l0.x, l0.y, l1.x, l1.y, l2.x, l2.y, l3.x, l3.y};
    ((f16x8*)xh)[tid] = h;
    ((f16x8*)xl)[tid] = l;
}

// ---------------------------------------------------------------------------
// Kernel 2: partial_h[kb][b][v] (f16) = sum over 1024-k slice of x*W.
// Grid: kb(32) x vg(16) = 512 blocks of 1024 threads (16 waves) = exactly
// 2 blocks/CU x 256 CUs. Wave w owns k = kb*1024 + w*64 .. +63:
// straight-line 4 ksteps, 16 VMEM (8 W float4 + 8 a-frag f16x8) issued
// together, 8 MFMAs (x hi + x lo per kstep).
// Epilogue: 16-wave LDS k-reduce -> one f16 32x32 tile per block.
// ---------------------------------------------------------------------------
__global__ __launch_bounds__(1024) void caps_mfma(
    const float* __restrict__ W, const __fp16* __restrict__ xh,
    const __fp16* __restrict__ xl, __fp16* __restrict__ partial_h)
{
    const int t    = threadIdx.x;
    const int lane = t & 63;
    const int wave = t >> 6;       // 0..15
    const int half = lane >> 5;    // 0/1: which 8-k group of a 16-k step
    const int ln32 = lane & 31;

    const int kb = blockIdx.x & (KB - 1);
    const int vg = blockIdx.x >> 5;
    const int v0 = vg * 32;
    const int k0 = kb * KSB + wave * KSW;
    const int g0 = (k0 >> 3) + half;     // k-group for kstep 0 (+2 per step)

    // issue all 16 VMEM back-to-back (straight-line, nothing to sink across)
    float4 w[2 * NST];
    f16x8  ah[NST], al[NST];
#pragma unroll
    for (int s = 0; s < NST; ++s) {
        const size_t g = (size_t)(g0 + 2 * s);
        const float4* wp = (const float4*)(W + (g * NV + v0 + ln32) * ND);
        w[2 * s]     = wp[0];
        w[2 * s + 1] = wp[1];
        ah[s] = *(const f16x8*)(xh + (g * 32 + ln32) * 8);
        al[s] = *(const f16x8*)(xl + (g * 32 + ln32) * 8);
    }

    f32x16 acc;
#pragma unroll
    for (int r = 0; r < 16; ++r) acc[r] = 0.0f;

#pragma unroll
    for (int s = 0; s < NST; ++s) {
        const f16x2 c01 = __builtin_amdgcn_cvt_pkrtz(w[2*s].x, w[2*s].y);
        const f16x2 c23 = __builtin_amdgcn_cvt_pkrtz(w[2*s].z, w[2*s].w);
        const f16x2 c45 = __builtin_amdgcn_cvt_pkrtz(w[2*s+1].x, w[2*s+1].y);
        const f16x2 c67 = __builtin_amdgcn_cvt_pkrtz(w[2*s+1].z, w[2*s+1].w);
        const f16x8 b = {c01.x, c01.y, c23.x, c23.y, c45.x, c45.y, c67.x, c67.y};
        acc = __builtin_amdgcn_mfma_f32_32x32x16_f16(ah[s], b, acc, 0, 0, 0);
        acc = __builtin_amdgcn_mfma_f32_32x32x16_f16(al[s], b, acc, 0, 0, 0);
    }

    // 16-wave k-reduce via LDS: wave w writes its 32x32 f32 tile, then
    // thread t sums element t across the 16 tiles and stores f16.
    __shared__ float red[16 * 1024];   // 64 KB
#pragma unroll
    for (int r = 0; r < 16; ++r)
        red[wave * 1024 + r * 64 + lane] = acc[r];
    __syncthreads();

    float val = 0.0f;
#pragma unroll
    for (int wv = 0; wv < 16; ++wv)    // 16 independent LDS reads
        val += red[wv * 1024 + t];

    const int r  = t >> 6;
    const int ln = t & 63;
    // C/D layout (m74/m101): col = lane&31 (v), row = (reg&3)+8*(reg>>2)+4*(lane>>5) (b)
    const int row = (r & 3) + 8 * (r >> 2) + 4 * (ln >> 5);
    const int col = ln & 31;
    partial_h[((size_t)kb * NB + row) * NV + v0 + col] = (__fp16)val;
}

// ---------------------------------------------------------------------------
// Kernel 3: reduce KB f16 slices + squash + write both outputs.
// Grid: 32 blocks (one per b) x 1024 threads. Thread t: v = t&511,
// kb-half = t>>9 (16 slices each) -> 2-way MLP; LDS combine; squash.
// ---------------------------------------------------------------------------
__global__ __launch_bounds__(1024) void caps_finish(
    const __fp16* __restrict__ partial_h, float* __restrict__ out)
{
    const int t = threadIdx.x;
    const int v = t & 511;
    const int h = t >> 9;              // 0/1: which half of the kb range
    const int b = blockIdx.x;

    float s = 0.0f;
#pragma unroll
    for (int g = 0; g < KB / 2; ++g)   // 16 independent coalesced loads
        s += (float)partial_h[((size_t)(h * (KB / 2) + g) * NB + b) * NV + v];

    __shared__ float sv[1024];
    sv[t] = s;
    __syncthreads();

    float sq = 0.0f;
    float stot = 0.0f;
    if (t < 512) {
        stot = sv[t] + sv[t + 512];
        sq = stot * stot;
    }
#pragma unroll
    for (int off = 32; off > 0; off >>= 1)
        sq += __shfl_xor(sq, off, 64);

    __shared__ float red[16];
    if ((t & 63) == 0) red[t >> 6] = sq;
    __syncthreads();
    if (t < 512) {
        float tot = 0.0f;
#pragma unroll
        for (int wv = 0; wv < 16; ++wv) tot += red[wv];  // waves 8..15 wrote 0

        // squash factor: sq/((1+sq)*sqrt(sq)) == sqrt(sq)/(1+sq)
        const float factor = sqrtf(tot) / (1.0f + tot);
        const float r = stot * factor;

        out[(size_t)b * NV + v]           = r;  // output 0: t       [B,1,V]
        out[NB * NV + (size_t)b * NV + v] = r;  // output 1: outputs [B,O,V]
    }
}

extern "C" void kernel_launch(void* const* d_in, const int* in_sizes, int n_in,
                              void* d_out, int out_size, void* d_ws, size_t ws_size,
                              hipStream_t stream) {
    const float* x = (const float*)d_in[0];   // [32, 4096, 8]
    const float* W = (const float*)d_in[1];   // [1, 4096, 512, 8]
    float* out     = (float*)d_out;           // 2 x [32,1,512] concatenated

    __fp16* xh       = (__fp16*)d_ws;                         // 2 MB
    __fp16* xl       = xh + (size_t)NB * NK;                  // 2 MB
    __fp16* partialh = xl + (size_t)NB * NK;                  // 1 MB (f16, KB=32)

    x_prep<<<(NB * NK / 8) / 256, 256, 0, stream>>>(x, xh, xl);
    caps_mfma<<<KB * 16, 1024, 0, stream>>>(W, xh, xl, partialh);
    caps_finish<<<NB, 1024, 0, stream>>>(partialh, out);
}

// Round 16
// 105.337 us; speedup vs baseline: 1.0127x; 1.0127x over previous
//
#include <hip/hip_runtime.h>
#include <stdint.h>

// DigitCaps with O=1: routing softmax over one out-capsule is identity, so
// the reference reduces to
//   s[b,v]  = sum_{i,d} W[i,v,d] * x[b,i,d]        (M=32, N=512, K=32768 GEMM)
//   out     = s * sqrt(sq)/(1+sq),  sq = sum_v s^2  (per-b squash)
// Both tuple outputs (t, outputs) are identical [32,1,512] tensors.
//
// R16 = revert to R14 (measured best: 105.4us). KSW sweep complete:
// 16->108.4, 32->105.4, 64->106.7 (VGPR pressure from 16 in-flight VMEM
// dests breaks 2-block/CU co-scheduling). Structural floor reached:
// ~82.5us harness 0xAA fills + ~10us W stream + ~6us prep/reduce/gaps.

#define NB 32
#define NI 4096
#define NV 512
#define ND 8
#define NK 32768            // K = NI*ND
#define KB 64               // k-blocks (partial slices)
#define KSB (NK / KB)       // 512 k per block (16 waves x 32)
#define KSW 32              // 32 k per wave = two 32x32x16 MFMA steps

typedef __fp16 f16x8 __attribute__((ext_vector_type(8)));
typedef __fp16 f16x2 __attribute__((ext_vector_type(2)));
typedef float  f32x16 __attribute__((ext_vector_type(16)));

// ---------------------------------------------------------------------------
// Kernel 1: split x (fp32 [32][32768]) into f16 hi/lo planes in FRAGMENT
// order: xt[(g*32 + b)*8 + j] where g=k>>3, j=k&7. hi = rtz(x); lo = x - hi.
// ---------------------------------------------------------------------------
__global__ __launch_bounds__(256) void x_prep(
    const float* __restrict__ x, __fp16* __restrict__ xh,
    __fp16* __restrict__ xl)
{
    const int tid = blockIdx.x * 256 + threadIdx.x;   // 131072 total
    const int b = tid & 31;
    const int g = tid >> 5;

    const float4* xp = (const float4*)(x + (size_t)b * NK + (size_t)g * 8);
    const float4 f0 = xp[0];
    const float4 f1 = xp[1];

    const f16x2 h0 = __builtin_amdgcn_cvt_pkrtz(f0.x, f0.y);
    const f16x2 h1 = __builtin_amdgcn_cvt_pkrtz(f0.z, f0.w);
    const f16x2 h2 = __builtin_amdgcn_cvt_pkrtz(f1.x, f1.y);
    const f16x2 h3 = __builtin_amdgcn_cvt_pkrtz(f1.z, f1.w);
    const f16x2 l0 = __builtin_amdgcn_cvt_pkrtz(f0.x - (float)h0.x, f0.y - (float)h0.y);
    const f16x2 l1 = __builtin_amdgcn_cvt_pkrtz(f0.z - (float)h1.x, f0.w - (float)h1.y);
    const f16x2 l2 = __builtin_amdgcn_cvt_pkrtz(f1.x - (float)h2.x, f1.y - (float)h2.y);
    const f16x2 l3 = __builtin_amdgcn_cvt_pkrtz(f1.z - (float)h3.x, f1.w - (float)h3.y);

    const f16x8 h = {h0.x, h0.y, h1.x, h1.y, h2.x, h2.y, h3.x, h3.y};
    const f16x8 l = {l0.x, l0.y, l1.x, l1.y, l2.x, l2.y, l3.x, l3.y};
    ((f16x8*)xh)[tid] = h;
    ((f16x8*)xl)[tid] = l;
}

// ---------------------------------------------------------------------------
// Kernel 2: partial_h[kb][b][v] (f16) = sum over 512-k slice of x*W.
// Grid: kb(64) x vg(16) = 1024 blocks of 1024 threads (16 waves).
// Wave w owns k = kb*512 + w*32 .. +31: straight-line 2 ksteps, 8 VMEM
// (4 W float4 + 4 a-frag f16x8) issued together, 4 MFMAs (hi+lo per kstep).
// Epilogue: 16-wave LDS k-reduce -> one f16 32x32 tile per block.
// ---------------------------------------------------------------------------
__global__ __launch_bounds__(1024) void caps_mfma(
    const float* __restrict__ W, const __fp16* __restrict__ xh,
    const __fp16* __restrict__ xl, __fp16* __restrict__ partial_h)
{
    const int t    = threadIdx.x;
    const int lane = t & 63;
    const int wave = t >> 6;       // 0..15
    const int half = lane >> 5;    // 0/1: which 8-k group of a 16-k step
    const int ln32 = lane & 31;

    const int kb = blockIdx.x & (KB - 1);
    const int vg = blockIdx.x >> 6;
    const int v0 = vg * 32;
    const int k0 = kb * KSB + wave * KSW;
    const int g0 = (k0 >> 3) + half;     // k-group for kstep 0
    const int g1 = g0 + 2;               // k-group for kstep 1

    const __fp16* ah0 = xh + ((size_t)g0 * 32 + ln32) * 8;
    const __fp16* al0 = xl + ((size_t)g0 * 32 + ln32) * 8;
    const float4* wp0 = (const float4*)(W + ((size_t)g0 * NV + v0 + ln32) * ND);
    const __fp16* ah1 = xh + ((size_t)g1 * 32 + ln32) * 8;
    const __fp16* al1 = xl + ((size_t)g1 * 32 + ln32) * 8;
    const float4* wp1 = (const float4*)(W + ((size_t)g1 * NV + v0 + ln32) * ND);

    // 8 VMEM issue back-to-back (straight-line, no loop to sink across)
    const float4 w00 = wp0[0];
    const float4 w01 = wp0[1];
    const float4 w10 = wp1[0];
    const float4 w11 = wp1[1];
    const f16x8 a0h = *(const f16x8*)ah0;
    const f16x8 a0l = *(const f16x8*)al0;
    const f16x8 a1h = *(const f16x8*)ah1;
    const f16x8 a1l = *(const f16x8*)al1;

    const f16x2 p01 = __builtin_amdgcn_cvt_pkrtz(w00.x, w00.y);
    const f16x2 p23 = __builtin_amdgcn_cvt_pkrtz(w00.z, w00.w);
    const f16x2 p45 = __builtin_amdgcn_cvt_pkrtz(w01.x, w01.y);
    const f16x2 p67 = __builtin_amdgcn_cvt_pkrtz(w01.z, w01.w);
    const f16x8 b0 = {p01.x, p01.y, p23.x, p23.y, p45.x, p45.y, p67.x, p67.y};
    const f16x2 q01 = __builtin_amdgcn_cvt_pkrtz(w10.x, w10.y);
    const f16x2 q23 = __builtin_amdgcn_cvt_pkrtz(w10.z, w10.w);
    const f16x2 q45 = __builtin_amdgcn_cvt_pkrtz(w11.x, w11.y);
    const f16x2 q67 = __builtin_amdgcn_cvt_pkrtz(w11.z, w11.w);
    const f16x8 b1 = {q01.x, q01.y, q23.x, q23.y, q45.x, q45.y, q67.x, q67.y};

    f32x16 acc;
#pragma unroll
    for (int r = 0; r < 16; ++r) acc[r] = 0.0f;
    acc = __builtin_amdgcn_mfma_f32_32x32x16_f16(a0h, b0, acc, 0, 0, 0);
    acc = __builtin_amdgcn_mfma_f32_32x32x16_f16(a0l, b0, acc, 0, 0, 0);
    acc = __builtin_amdgcn_mfma_f32_32x32x16_f16(a1h, b1, acc, 0, 0, 0);
    acc = __builtin_amdgcn_mfma_f32_32x32x16_f16(a1l, b1, acc, 0, 0, 0);

    // 16-wave k-reduce via LDS: wave w writes its 32x32 f32 tile, then
    // thread t sums element t across the 16 tiles and stores f16.
    __shared__ float red[16 * 1024];   // 64 KB
#pragma unroll
    for (int r = 0; r < 16; ++r)
        red[wave * 1024 + r * 64 + lane] = acc[r];
    __syncthreads();

    float val = 0.0f;
#pragma unroll
    for (int w = 0; w < 16; ++w)       // 16 independent LDS reads
        val += red[w * 1024 + t];

    const int r  = t >> 6;
    const int ln = t & 63;
    // C/D layout (m74/m101): col = lane&31 (v), row = (reg&3)+8*(reg>>2)+4*(lane>>5) (b)
    const int row = (r & 3) + 8 * (r >> 2) + 4 * (ln >> 5);
    const int col = ln & 31;
    partial_h[((size_t)kb * NB + row) * NV + v0 + col] = (__fp16)val;
}

// ---------------------------------------------------------------------------
// Kernel 3: reduce KB f16 slices + squash + write both outputs.
// Grid: 32 blocks (one per b) x 1024 threads. Thread t: v = t&511,
// kb-half = t>>9 (32 slices each) -> 2-way MLP; LDS combine; squash.
// ---------------------------------------------------------------------------
__global__ __launch_bounds__(1024) void caps_finish(
    const __fp16* __restrict__ partial_h, float* __restrict__ out)
{
    const int t = threadIdx.x;
    const int v = t & 511;
    const int h = t >> 9;              // 0/1: which half of the kb range
    const int b = blockIdx.x;

    float s = 0.0f;
#pragma unroll
    for (int g = 0; g < KB / 2; ++g)   // 32 independent coalesced loads
        s += (float)partial_h[((size_t)(h * (KB / 2) + g) * NB + b) * NV + v];

    __shared__ float sv[1024];
    sv[t] = s;
    __syncthreads();

    float sq = 0.0f;
    float stot = 0.0f;
    if (t < 512) {
        stot = sv[t] + sv[t + 512];
        sq = stot * stot;
    }
#pragma unroll
    for (int off = 32; off > 0; off >>= 1)
        sq += __shfl_xor(sq, off, 64);

    __shared__ float red[16];
    if ((t & 63) == 0) red[t >> 6] = sq;
    __syncthreads();
    if (t < 512) {
        float tot = 0.0f;
#pragma unroll
        for (int wv = 0; wv < 16; ++wv) tot += red[wv];  // waves 8..15 wrote 0

        // squash factor: sq/((1+sq)*sqrt(sq)) == sqrt(sq)/(1+sq)
        const float factor = sqrtf(tot) / (1.0f + tot);
        const float r = stot * factor;

        out[(size_t)b * NV + v]           = r;  // output 0: t       [B,1,V]
        out[NB * NV + (size_t)b * NV + v] = r;  // output 1: outputs [B,O,V]
    }
}

extern "C" void kernel_launch(void* const* d_in, const int* in_sizes, int n_in,
                              void* d_out, int out_size, void* d_ws, size_t ws_size,
                              hipStream_t stream) {
    const float* x = (const float*)d_in[0];   // [32, 4096, 8]
    const float* W = (const float*)d_in[1];   // [1, 4096, 512, 8]
    float* out     = (float*)d_out;           // 2 x [32,1,512] concatenated

    __fp16* xh       = (__fp16*)d_ws;                         // 2 MB
    __fp16* xl       = xh + (size_t)NB * NK;                  // 2 MB
    __fp16* partialh = xl + (size_t)NB * NK;                  // 2 MB (f16, KB=64)

    x_prep<<<(NB * NK / 8) / 256, 256, 0, stream>>>(x, xh, xl);
    caps_mfma<<<KB * 16, 1024, 0, stream>>>(W, xh, xl, partialh);
    caps_finish<<<NB, 1024, 0, stream>>>(partialh, out);
}